// Round 9
// baseline (8199.821 us; speedup 1.0000x reference)
//
#include <hip/hip_runtime.h>
#include <math.h>

// Problem constants (reference: BS=32, N=M=1024, eps=0.1, 200 iters)
#define BS    32
#define N     1024
#define M     1024
#define ITERS 200

// 16 WGs per batch, 256 threads (4 waves) -> grid 512 = 2 blocks/CU.
// The two co-resident blocks serve DIFFERENT batches: while one sits in its
// inter-WG exchange, the CU runs the other's sweep (hardware overlap, no
// extra syncs -- the R7 mistake inverted). 64 rows per WG: 28 in LDS (56 KB),
// 36 streamed from u16 cq (72 KB/WG -> 4.6 MB/XCD, ~L2-resident).
// NO register payload (R5/R8 lesson: allocator refuses >128 VGPRs here).
#define WPB   16
#define T     256
#define NW    4
#define RS    9                  // streamed rows per wave
#define RL    7                  // LDS rows per wave
#define SROWS (NW * RS)          // 36 streamed rows per WG
#define LROWS (NW * RL)          // 28 LDS rows per WG

// ws layout: flags (padded, 128B per WG) + partials + streamed cq
#define FLAGS_BYTES ((size_t)65536)              // [BS*WPB] u32, 32-u32 pitch
#define PART_OFF    ((size_t)FLAGS_BYTES)
#define PART_BYTES  ((size_t)2 * BS * WPB * M * 4)   // 4 MB double-buffered
#define CQ_OFF      (PART_OFF + PART_BYTES)
#define CQ_BYTES    ((size_t)BS * WPB * SROWS * M * 2)  // 36 MB
#define WS_NEEDED   (CQ_OFF + CQ_BYTES)

// unpack two u16 from a 32-bit word to floats (raw, unscaled)
__device__ __forceinline__ float2 upair(unsigned w) {
    return make_float2((float)(w & 0xffffu), (float)(w >> 16));
}

// Ghat = round(65535 * exp(-10*C)); the 1/65535 scales cancel algebraically:
//   u' = MU/(Ghat.v) == u/65535 ; col = sum u'*Ghat == u^T G ;
//   Gamma*n = u' * Ghat * v * N
__device__ __forceinline__ unsigned qq(float c0, float c1) {
    const float KE = -14.4269504088896340f;   // -10*log2(e)
    unsigned a = __float2uint_rn(65535.0f * __builtin_amdgcn_exp2f(KE * c0));
    unsigned b = __float2uint_rn(65535.0f * __builtin_amdgcn_exp2f(KE * c1));
    return a | (b << 16);
}

__global__ __launch_bounds__(T, 2) void sinkhorn_dual(
    const float* __restrict__ C,
    float* __restrict__ Gout,            // d_out: final Gamma*n only
    unsigned* __restrict__ flags,        // [BS*WPB] pitch 32 u32 (128 B)
    float* __restrict__ partials,        // [2][BS][WPB][M]
    unsigned short* __restrict__ cq)     // [BS][WPB][SROWS][M] u16, permuted
{
    const int bid  = blockIdx.x;
    const int b    = bid & 31;           // batch; bid%8 == b%8 -> one XCD
    const int k    = bid >> 5;           // slice 0..15
    const int tid  = threadIdx.x;
    const int lane = tid & 63;
    const int wave = tid >> 6;

    const float MU = 1.0f / (float)N;
    const float NU = 1.0f / (float)M;

    // LDS: 57344 (G) + 16384 (combine) + 4096 (v) = 76 KB -> 2 blocks/CU fit
    __shared__ uint4 Glds[LROWS][M / 8];
    __shared__ float part[NW][M];
    __shared__ float v_lds[M];

    const size_t slC = ((size_t)b * N + (size_t)k * 64) * M;   // C/Gout slice
    uint4* cq4 = (uint4*)cq + ((size_t)(b * WPB + k) * SROWS) * (M / 8);

    // ---- prologue: quantize 64 rows (36 -> cq global, 28 -> LDS) ----
    #pragma unroll
    for (int i = 0; i < RS; ++i) {
        const int rl = wave * 16 + i;                 // local row 0..63
        const float4* cr = (const float4*)(C + slC + (size_t)rl * M);
        float4 a0 = cr[lane],       a1 = cr[64 + lane];
        float4 b0 = cr[128 + lane], b1 = cr[192 + lane];
        uint4 oa, ob;
        oa.x = qq(a0.x, a0.y);  oa.y = qq(a0.z, a0.w);
        oa.z = qq(a1.x, a1.y);  oa.w = qq(a1.z, a1.w);
        ob.x = qq(b0.x, b0.y);  ob.y = qq(b0.z, b0.w);
        ob.z = qq(b1.x, b1.y);  ob.w = qq(b1.z, b1.w);
        cq4[(size_t)(wave * RS + i) * 128 + lane]      = oa;
        cq4[(size_t)(wave * RS + i) * 128 + 64 + lane] = ob;
    }
    #pragma unroll
    for (int j = 0; j < RL; ++j) {
        const int rl = wave * 16 + RS + j;
        const float4* cr = (const float4*)(C + slC + (size_t)rl * M);
        float4 a0 = cr[lane],       a1 = cr[64 + lane];
        float4 b0 = cr[128 + lane], b1 = cr[192 + lane];
        uint4 oa, ob;
        oa.x = qq(a0.x, a0.y);  oa.y = qq(a0.z, a0.w);
        oa.z = qq(a1.x, a1.y);  oa.w = qq(a1.z, a1.w);
        ob.x = qq(b0.x, b0.y);  ob.y = qq(b0.z, b0.w);
        ob.z = qq(b1.x, b1.y);  ob.w = qq(b1.z, b1.w);
        Glds[wave * RL + j][lane]      = oa;
        Glds[wave * RL + j][64 + lane] = ob;
    }
    ((float4*)v_lds)[tid] = make_float4(NU, NU, NU, NU);
    __syncthreads();

    // Stagger: co-resident blocks differ in b by 8 (round-robin model);
    // offset one of them ~1.7us so exchange phases interleave with the
    // sibling's sweep. Perf-only; barriers enforce correctness regardless.
    if ((b >> 3) & 1) __builtin_amdgcn_s_sleep(63);

    unsigned* myflag = flags + (size_t)(b * WPB + k) * 32;
    const float4* v4 = (const float4*)v_lds;
    float4 vra0 = v4[lane],       vra1 = v4[64 + lane],
           vrb0 = v4[128 + lane], vrb1 = v4[192 + lane];

    float ureg[16];   // u for own 16 rows (static idx; all lanes hold it)

    for (int t = 0; t < ITERS; ++t) {
        const int par = t & 1;
        float4 ca0 = make_float4(0,0,0,0), ca1 = make_float4(0,0,0,0),
               cb0 = make_float4(0,0,0,0), cb1 = make_float4(0,0,0,0);

        auto dorow = [&](uint4 qa, uint4 qb) -> float {
            float2 g0 = upair(qa.x), g1 = upair(qa.y),
                   g2 = upair(qa.z), g3 = upair(qa.w);
            float2 h0 = upair(qb.x), h1 = upair(qb.y),
                   h2 = upair(qb.z), h3 = upair(qb.w);
            float pa = (g0.x*vra0.x + g0.y*vra0.y) + (g1.x*vra0.z + g1.y*vra0.w);
            float pb = (g2.x*vra1.x + g2.y*vra1.y) + (g3.x*vra1.z + g3.y*vra1.w);
            float pc = (h0.x*vrb0.x + h0.y*vrb0.y) + (h1.x*vrb0.z + h1.y*vrb0.w);
            float pd = (h2.x*vrb1.x + h2.y*vrb1.y) + (h3.x*vrb1.z + h3.y*vrb1.w);
            float dot = (pa + pb) + (pc + pd);
            #pragma unroll
            for (int off = 32; off > 0; off >>= 1)
                dot += __shfl_xor(dot, off, 64);
            float ui = MU / dot;     // identical in all 64 lanes
            ca0.x += ui*g0.x; ca0.y += ui*g0.y; ca0.z += ui*g1.x; ca0.w += ui*g1.y;
            ca1.x += ui*g2.x; ca1.y += ui*g2.y; ca1.z += ui*g3.x; ca1.w += ui*g3.y;
            cb0.x += ui*h0.x; cb0.y += ui*h0.y; cb0.z += ui*h1.x; cb0.w += ui*h1.y;
            cb1.x += ui*h2.x; cb1.y += ui*h2.y; cb1.z += ui*h3.x; cb1.w += ui*h3.y;
            return ui;
        };

        // ---- fused sweep: 9 streamed + 7 LDS rows per wave ----
        #pragma unroll
        for (int i = 0; i < RS; ++i) {
            uint4 sa = cq4[(size_t)(wave * RS + i) * 128 + lane];
            uint4 sb = cq4[(size_t)(wave * RS + i) * 128 + 64 + lane];
            ureg[i] = dorow(sa, sb);
        }
        #pragma unroll
        for (int j = 0; j < RL; ++j) {
            uint4 la = Glds[wave * RL + j][lane];
            uint4 lb = Glds[wave * RL + j][64 + lane];
            ureg[RS + j] = dorow(la, lb);
        }

        // ---- combine 4 waves (1 sync), write WG partial (coalesced) ----
        {
            float4* p4 = (float4*)part[wave];
            p4[lane]       = ca0;
            p4[64 + lane]  = ca1;
            p4[128 + lane] = cb0;
            p4[192 + lane] = cb1;
        }
        __syncthreads();
        {
            const float2* q0 = (const float2*)part[0];
            const float2* q1 = (const float2*)part[1];
            const float2* q2 = (const float2*)part[2];
            const float2* q3 = (const float2*)part[3];
            float2* pg = (float2*)(partials +
                (((size_t)par * BS + b) * WPB + k) * M);
            float2 a0 = q0[tid], a1 = q1[tid], a2 = q2[tid], a3 = q3[tid];
            pg[tid] = make_float2((a0.x + a1.x) + (a2.x + a3.x),
                                  (a0.y + a1.y) + (a2.y + a3.y));
            float2 c0 = q0[256 + tid], c1 = q1[256 + tid],
                   c2 = q2[256 + tid], c3 = q3[256 + tid];
            pg[256 + tid] = make_float2((c0.x + c1.x) + (c2.x + c3.x),
                                        (c0.y + c1.y) + (c2.y + c3.y));
        }
        __syncthreads();   // all partial stores issued before the release
        // ---- flag barrier: 16 parallel store-releases, 16-lane poll ----
        if (tid == 0)
            __hip_atomic_store(myflag, (unsigned)(t + 1), __ATOMIC_RELEASE,
                               __HIP_MEMORY_SCOPE_AGENT);
        if (wave == 0 && lane < WPB) {
            const unsigned tgt = (unsigned)(t + 1);
            while (__hip_atomic_load(flags + (size_t)(b * WPB + lane) * 32,
                                     __ATOMIC_ACQUIRE,
                                     __HIP_MEMORY_SCOPE_AGENT) < tgt)
                __builtin_amdgcn_s_sleep(1);
        }
        __syncthreads();
        // ---- v = NU / sum of 16 WG partials (fixed order: bitwise-
        //      identical in all WGs of the batch) ----
        {
            const float2* pall = (const float2*)(partials +
                ((size_t)par * BS + b) * ((size_t)WPB * M));
            float sx0 = 0.f, sy0 = 0.f, sx1 = 0.f, sy1 = 0.f;
            #pragma unroll
            for (int p = 0; p < WPB; ++p) {
                float2 qa = pall[(size_t)p * 512 + tid];
                float2 qb = pall[(size_t)p * 512 + 256 + tid];
                sx0 += qa.x; sy0 += qa.y;
                sx1 += qb.x; sy1 += qb.y;
            }
            float2* v2 = (float2*)v_lds;
            v2[tid]       = make_float2(NU / sx0, NU / sy0);
            v2[256 + tid] = make_float2(NU / sx1, NU / sy1);
        }
        __syncthreads();
        vra0 = v4[lane];       vra1 = v4[64 + lane];
        vrb0 = v4[128 + lane]; vrb1 = v4[192 + lane];
    }

    // ---- epilogue: Gamma*n = u' * Ghat * v * N (scales cancel) ----
    const float nN = (float)N;
    auto emit = [&](float* rowp, uint4 qa, uint4 qb, float un) {
        float2 g0 = upair(qa.x), g1 = upair(qa.y),
               g2 = upair(qa.z), g3 = upair(qa.w);
        float2 h0 = upair(qb.x), h1 = upair(qb.y),
               h2 = upair(qb.z), h3 = upair(qb.w);
        float4* o4 = (float4*)rowp;
        o4[lane]       = make_float4(un*g0.x*vra0.x, un*g0.y*vra0.y,
                                     un*g1.x*vra0.z, un*g1.y*vra0.w);
        o4[64 + lane]  = make_float4(un*g2.x*vra1.x, un*g2.y*vra1.y,
                                     un*g3.x*vra1.z, un*g3.y*vra1.w);
        o4[128 + lane] = make_float4(un*h0.x*vrb0.x, un*h0.y*vrb0.y,
                                     un*h1.x*vrb0.z, un*h1.y*vrb0.w);
        o4[192 + lane] = make_float4(un*h2.x*vrb1.x, un*h2.y*vrb1.y,
                                     un*h3.x*vrb1.z, un*h3.y*vrb1.w);
    };
    #pragma unroll
    for (int i = 0; i < RS; ++i) {
        const int rl = wave * 16 + i;
        uint4 sa = cq4[(size_t)(wave * RS + i) * 128 + lane];
        uint4 sb = cq4[(size_t)(wave * RS + i) * 128 + 64 + lane];
        emit(Gout + slC + (size_t)rl * M, sa, sb, ureg[i] * nN);
    }
    #pragma unroll
    for (int j = 0; j < RL; ++j) {
        const int rl = wave * 16 + RS + j;
        uint4 la = Glds[wave * RL + j][lane];
        uint4 lb = Glds[wave * RL + j][64 + lane];
        emit(Gout + slC + (size_t)rl * M, la, lb, ureg[RS + j] * nN);
    }
}

extern "C" void kernel_launch(void* const* d_in, const int* in_sizes, int n_in,
                              void* d_out, int out_size, void* d_ws, size_t ws_size,
                              hipStream_t stream) {
    (void)in_sizes; (void)n_in; (void)out_size;

    const float* C = (const float*)d_in[0];
    float* Gout = (float*)d_out;
    char* ws = (char*)d_ws;

    if (ws_size < WS_NEEDED) return;   // fail loudly (output stays poisoned)

    // Re-zero flags every launch (graph-replay safe, deterministic).
    hipMemsetAsync(d_ws, 0, FLAGS_BYTES, stream);

    unsigned* flags      = (unsigned*)ws;
    float* partials      = (float*)(ws + PART_OFF);
    unsigned short* cq   = (unsigned short*)(ws + CQ_OFF);
    sinkhorn_dual<<<dim3(BS * WPB), dim3(T), 0, stream>>>(
        C, Gout, flags, partials, cq);
}

// Round 10
// 6627.246 us; speedup vs baseline: 1.2373x; 1.2373x over previous
//
#include <hip/hip_runtime.h>
#include <math.h>

// Problem constants (reference: BS=32, N=M=1024, eps=0.1, 200 iters)
#define BS    32
#define N     1024
#define M     1024
#define ITERS 200

// R4's proven minimal skeleton, unchanged:
//   8 WGs per batch, 512 threads, grid 256 = 1 WG/CU, 3 intra-WG syncs,
//   one 8-wide atomic inter-WG barrier, flat 8-way v-reduce.
// Single delta vs R4: 56 of the 128 rows/WG live in LDS as packed u16
// (112 KB), only 72 rows stream from the u16 cq buffer (144 KB/WG/iter,
// -44% sweep bytes). No register payload (R5/R8/R9: allocator spills).
#define WPB   8
#define ROWS  (N / WPB)      // 128 rows per WG
#define T     512            // 8 waves
#define NW    8
#define RL    7              // LDS rows per wave  (56 per WG)
#define RS    9              // streamed rows per wave (72 per WG)
#define SROWS (NW * RS)

// ws: counters + double-buffered partials [2][BS][WPB][M] + streamed cq
#define CNT_BYTES  4096
#define PART_OFF   ((size_t)CNT_BYTES)
#define PART_BYTES ((size_t)2 * BS * WPB * M * 4)          // 2 MB
#define CQ_OFF     (PART_OFF + PART_BYTES)
#define CQ_BYTES   ((size_t)BS * WPB * SROWS * M * 2)      // 36 MB
#define WS_NEEDED  (CQ_OFF + CQ_BYTES)

// unpack two u16 from a 32-bit word to floats (raw, unscaled)
__device__ __forceinline__ float2 upair(unsigned w) {
    return make_float2((float)(w & 0xffffu), (float)(w >> 16));
}

// Ghat = round(65535 * exp(-10*C)); the 1/65535 scales cancel algebraically:
//   u' = MU/(Ghat.v) == u/65535 ; col = sum u'*Ghat == u^T G ;
//   Gamma*n = u' * Ghat * v * N
__device__ __forceinline__ unsigned qq(float c0, float c1) {
    const float KE = -14.4269504088896340f;   // -10*log2(e)
    unsigned a = __float2uint_rn(65535.0f * __builtin_amdgcn_exp2f(KE * c0));
    unsigned b = __float2uint_rn(65535.0f * __builtin_amdgcn_exp2f(KE * c1));
    return a | (b << 16);
}

// Permuted layout per row (128 uint4 slots): slot h*64+l holds cols
// {512h+4l..+3} and {512h+256+4l..+3} -> all accesses contiguous per lane.
__global__ __launch_bounds__(T) void sinkhorn_q16c(
    const float* __restrict__ C,
    float* __restrict__ Gout,            // d_out: final Gamma*n only
    unsigned* __restrict__ cnt,          // [BS] stride-32 uints
    float* __restrict__ partials,        // [2][BS][WPB][M]
    unsigned short* __restrict__ cq)     // [BS*WPB][SROWS][M] u16 permuted
{
    const int bid  = blockIdx.x;
    const int b    = bid & (BS - 1);   // all 8 WGs of a batch: bid%8 == b%8
    const int k    = bid >> 5;         // 0..7  (co-located per XCD model)
    const int tid  = threadIdx.x;
    const int lane = tid & 63;
    const int wave = tid >> 6;

    const size_t sl = ((size_t)b * N + (size_t)k * ROWS) * M;
    const float MU = 1.0f / (float)N;
    const float NU = 1.0f / (float)M;

    // LDS: 114688 (G, 56 rows) + 32768 (part) + 4096 (v) + 512 (u) = 148.5 KB
    __shared__ uint4 Glds[NW * RL][M / 8];
    __shared__ float part[NW][M];
    __shared__ float v_lds[M];
    __shared__ float u_lds[ROWS];

    uint4* cq4 = (uint4*)cq + (size_t)(b * WPB + k) * SROWS * (M / 8);

    // ---- prologue: quantize own 128 rows (56 -> LDS, 72 -> cq) ----
    #pragma unroll
    for (int rr = 0; rr < 16; ++rr) {
        const int row = wave * 16 + rr;
        const float4* cr = (const float4*)(C + sl + (size_t)row * M);
        float4 a0 = cr[lane],       a1 = cr[64 + lane];
        float4 b0 = cr[128 + lane], b1 = cr[192 + lane];
        uint4 oa, ob;
        oa.x = qq(a0.x, a0.y);  oa.y = qq(a0.z, a0.w);
        oa.z = qq(a1.x, a1.y);  oa.w = qq(a1.z, a1.w);
        ob.x = qq(b0.x, b0.y);  ob.y = qq(b0.z, b0.w);
        ob.z = qq(b1.x, b1.y);  ob.w = qq(b1.z, b1.w);
        if (rr < RL) {
            Glds[wave * RL + rr][lane]      = oa;
            Glds[wave * RL + rr][64 + lane] = ob;
        } else {
            cq4[(size_t)(wave * RS + (rr - RL)) * 128 + lane]      = oa;
            cq4[(size_t)(wave * RS + (rr - RL)) * 128 + 64 + lane] = ob;
        }
    }
    ((float2*)v_lds)[tid] = make_float2(NU, NU);
    __syncthreads();

    unsigned* mycnt = cnt + b * 32;
    const float4* v4 = (const float4*)v_lds;
    float4 vra0 = v4[lane],       vra1 = v4[64 + lane],
           vrb0 = v4[128 + lane], vrb1 = v4[192 + lane];

    for (int t = 0; t < ITERS; ++t) {
        const int par = t & 1;
        float4 ca0 = make_float4(0,0,0,0), ca1 = make_float4(0,0,0,0),
               cb0 = make_float4(0,0,0,0), cb1 = make_float4(0,0,0,0);

        auto dorow = [&](uint4 qa, uint4 qb, int row) {
            float2 g0 = upair(qa.x), g1 = upair(qa.y),
                   g2 = upair(qa.z), g3 = upair(qa.w);
            float2 h0 = upair(qb.x), h1 = upair(qb.y),
                   h2 = upair(qb.z), h3 = upair(qb.w);
            float pa = (g0.x*vra0.x + g0.y*vra0.y) + (g1.x*vra0.z + g1.y*vra0.w);
            float pb = (g2.x*vra1.x + g2.y*vra1.y) + (g3.x*vra1.z + g3.y*vra1.w);
            float pc = (h0.x*vrb0.x + h0.y*vrb0.y) + (h1.x*vrb0.z + h1.y*vrb0.w);
            float pd = (h2.x*vrb1.x + h2.y*vrb1.y) + (h3.x*vrb1.z + h3.y*vrb1.w);
            float dot = (pa + pb) + (pc + pd);
            #pragma unroll
            for (int off = 32; off > 0; off >>= 1)
                dot += __shfl_xor(dot, off, 64);
            const float ui = MU / dot;
            if (lane == 0) u_lds[row] = ui;
            ca0.x += ui*g0.x; ca0.y += ui*g0.y; ca0.z += ui*g1.x; ca0.w += ui*g1.y;
            ca1.x += ui*g2.x; ca1.y += ui*g2.y; ca1.z += ui*g3.x; ca1.w += ui*g3.y;
            cb0.x += ui*h0.x; cb0.y += ui*h0.y; cb0.z += ui*h1.x; cb0.w += ui*h1.y;
            cb1.x += ui*h2.x; cb1.y += ui*h2.y; cb1.z += ui*h3.x; cb1.w += ui*h3.y;
        };

        // ---- fused sweep: 9 streamed rows then 7 LDS rows per wave ----
        #pragma unroll
        for (int i = 0; i < RS; ++i) {
            uint4 sa = cq4[(size_t)(wave * RS + i) * 128 + lane];
            uint4 sb = cq4[(size_t)(wave * RS + i) * 128 + 64 + lane];
            dorow(sa, sb, wave * 16 + RL + i);
        }
        #pragma unroll
        for (int j = 0; j < RL; ++j) {
            uint4 la = Glds[wave * RL + j][lane];
            uint4 lb = Glds[wave * RL + j][64 + lane];
            dorow(la, lb, wave * 16 + j);
        }

        // ---- combine 8 waves (R4 structure, unchanged) ----
        {
            float4* pw = (float4*)part[wave];
            pw[lane]       = ca0;
            pw[64 + lane]  = ca1;
            pw[128 + lane] = cb0;
            pw[192 + lane] = cb1;
        }
        __syncthreads();
        {
            float2 s = make_float2(0.0f, 0.0f);
            #pragma unroll
            for (int w = 0; w < NW; ++w) {
                float2 q = ((const float2*)part[w])[tid];
                s.x += q.x; s.y += q.y;
            }
            float2* pg = (float2*)(partials +
                (((size_t)par * BS + b) * WPB + k) * M);
            pg[tid] = s;
        }
        __syncthreads();
        // ---- single 8-wide inter-WG barrier for this batch ----
        if (tid == 0) {
            __hip_atomic_fetch_add(mycnt, 1u, __ATOMIC_RELEASE,
                                   __HIP_MEMORY_SCOPE_AGENT);
            const unsigned tgt = (unsigned)WPB * (unsigned)(t + 1);
            while (__hip_atomic_load(mycnt, __ATOMIC_ACQUIRE,
                                     __HIP_MEMORY_SCOPE_AGENT) < tgt)
                __builtin_amdgcn_s_sleep(1);
        }
        __syncthreads();
        // ---- v = NU / sum_p partial[p]  (fixed order, all threads) ----
        {
            const float2* pall = (const float2*)(partials +
                ((size_t)par * BS + b) * ((size_t)WPB * M));
            float2 s = pall[tid];
            #pragma unroll
            for (int p = 1; p < WPB; ++p) {
                float2 q = pall[(size_t)p * (M / 2) + tid];
                s.x += q.x; s.y += q.y;
            }
            ((float2*)v_lds)[tid] = make_float2(NU / s.x, NU / s.y);
        }
        __syncthreads();
        vra0 = v4[lane];       vra1 = v4[64 + lane];
        vrb0 = v4[128 + lane]; vrb1 = v4[192 + lane];
    }

    // ---- epilogue: Gamma*n = u' * Ghat * v * N (scales cancel) ----
    const float nN = (float)N;
    auto emit = [&](float* rowp, uint4 qa, uint4 qb, float un) {
        float2 g0 = upair(qa.x), g1 = upair(qa.y),
               g2 = upair(qa.z), g3 = upair(qa.w);
        float2 h0 = upair(qb.x), h1 = upair(qb.y),
               h2 = upair(qb.z), h3 = upair(qb.w);
        float4* o4 = (float4*)rowp;
        o4[lane]       = make_float4(un*g0.x*vra0.x, un*g0.y*vra0.y,
                                     un*g1.x*vra0.z, un*g1.y*vra0.w);
        o4[64 + lane]  = make_float4(un*g2.x*vra1.x, un*g2.y*vra1.y,
                                     un*g3.x*vra1.z, un*g3.y*vra1.w);
        o4[128 + lane] = make_float4(un*h0.x*vrb0.x, un*h0.y*vrb0.y,
                                     un*h1.x*vrb0.z, un*h1.y*vrb0.w);
        o4[192 + lane] = make_float4(un*h2.x*vrb1.x, un*h2.y*vrb1.y,
                                     un*h3.x*vrb1.z, un*h3.y*vrb1.w);
    };
    #pragma unroll
    for (int i = 0; i < RS; ++i) {
        const int row = wave * 16 + RL + i;
        uint4 sa = cq4[(size_t)(wave * RS + i) * 128 + lane];
        uint4 sb = cq4[(size_t)(wave * RS + i) * 128 + 64 + lane];
        emit(Gout + sl + (size_t)row * M, sa, sb, u_lds[row] * nN);
    }
    #pragma unroll
    for (int j = 0; j < RL; ++j) {
        const int row = wave * 16 + j;
        uint4 la = Glds[wave * RL + j][lane];
        uint4 lb = Glds[wave * RL + j][64 + lane];
        emit(Gout + sl + (size_t)row * M, la, lb, u_lds[row] * nN);
    }
}

extern "C" void kernel_launch(void* const* d_in, const int* in_sizes, int n_in,
                              void* d_out, int out_size, void* d_ws, size_t ws_size,
                              hipStream_t stream) {
    (void)in_sizes; (void)n_in; (void)out_size;

    const float* C = (const float*)d_in[0];
    float* Gout = (float*)d_out;
    char* ws = (char*)d_ws;

    if (ws_size < WS_NEEDED) return;   // fail loudly (output stays poisoned)

    // Re-zero barrier counters every launch (graph-replay safe).
    hipMemsetAsync(d_ws, 0, CNT_BYTES, stream);

    unsigned* cnt      = (unsigned*)ws;
    float* partials    = (float*)(ws + PART_OFF);
    unsigned short* cq = (unsigned short*)(ws + CQ_OFF);
    sinkhorn_q16c<<<dim3(BS * WPB), dim3(T), 0, stream>>>(
        C, Gout, cnt, partials, cq);
}